// Round 4
// baseline (837.055 us; speedup 1.0000x reference)
//
#include <hip/hip_runtime.h>
#include <hip/hip_bf16.h>
#include <cmath>

// Problem constants (fixed by setup_inputs)
constexpr int S = 128;   // num_states
constexpr int C = 32;    // num_chains
constexpr int N = 4096;  // num_nodes
constexpr int T = 512;   // num_iters

// Output layout (flat float32, concatenated in reference return order)
constexpr size_t OFF1 = 0;                          // log_observed_state_probs  [T,N]
constexpr size_t OFF2 = OFF1 + (size_t)T * N;       // log_observed_state_probs_ [T,C,N]
constexpr size_t OFF3 = OFF2 + (size_t)T * C * N;   // log_hidden_state_probs   [T,C,S]
constexpr size_t OFF4 = OFF3 + (size_t)T * C * S;   // log_emission             [S,N]
constexpr size_t OFF5 = OFF4 + (size_t)S * N;       // log_chain_weights        [T,C]

typedef __bf16 bf16x8 __attribute__((ext_vector_type(8)));
typedef float floatx4 __attribute__((ext_vector_type(4)));
typedef float floatx16 __attribute__((ext_vector_type(16)));

__device__ __forceinline__ void split_bf16(float p, __bf16& hi, __bf16& lo) {
    hi = (__bf16)p;
    lo = (__bf16)(p - (float)hi);
}

// ---------------------------------------------------------------------------
// Fused softmax kernel, one launch, 352 blocks x 256 threads.
// Also zeroes the sync/flag words used by the mega kernel (block 0).
// ---------------------------------------------------------------------------
__global__ __launch_bounds__(256) void fused_softmax_kernel(
        const float* __restrict__ emis, const float* __restrict__ cw,
        const float* __restrict__ trans, const float* __restrict__ init,
        float* __restrict__ out3, float* __restrict__ out4, float* __restrict__ out5,
        __bf16* __restrict__ pET, float* __restrict__ pcw,
        __bf16* __restrict__ Rhi, __bf16* __restrict__ Rlo,
        __bf16* __restrict__ Thi, __bf16* __restrict__ Tlo,
        __bf16* __restrict__ Hhi, __bf16* __restrict__ Hlo,
        unsigned* __restrict__ sync_) {
    const int b = blockIdx.x;
    const int tid = threadIdx.x;

    if (b == 0 && tid == 0) {      // zero flags before mega (kernel boundary = fence)
        for (int i = 0; i < 12; ++i) sync_[i] = 0;
    }

    if (b >= 288) {   // ---- chain weights: 8 rows of 32 per block ----
        const int row = (b - 288) * 8 + (tid >> 5);
        const int j = tid & 31;
        const float v = cw[(size_t)row * C + j];
        float m = v;
#pragma unroll
        for (int o = 16; o > 0; o >>= 1) m = fmaxf(m, __shfl_xor(m, o, 64));
        float s = __expf(v - m);
#pragma unroll
        for (int o = 16; o > 0; o >>= 1) s += __shfl_xor(s, o, 64);
        const float lv = v - m - __logf(s);
        out5[(size_t)row * C + j] = lv;
        pcw[(size_t)row * C + j] = __expf(lv);
        return;
    }

    const float* x;
    int cols, row;
    if (b < 128)      { row = b;       cols = N; x = emis  + (size_t)row * N; }
    else if (b < 256) { row = b - 128; cols = S; x = trans + (size_t)row * S; }
    else              { row = b - 256; cols = S; x = init  + (size_t)row * S; }

    __shared__ float sm[4];
    __shared__ float ss[4];

    float m = -INFINITY;
    for (int j = tid; j < cols; j += 256) m = fmaxf(m, x[j]);
#pragma unroll
    for (int o = 32; o > 0; o >>= 1) m = fmaxf(m, __shfl_xor(m, o, 64));
    const int wid = tid >> 6;
    if ((tid & 63) == 0) sm[wid] = m;
    __syncthreads();
    m = fmaxf(fmaxf(sm[0], sm[1]), fmaxf(sm[2], sm[3]));

    float s = 0.f;
    for (int j = tid; j < cols; j += 256) s += __expf(x[j] - m);
#pragma unroll
    for (int o = 32; o > 0; o >>= 1) s += __shfl_xor(s, o, 64);
    if ((tid & 63) == 0) ss[wid] = s;
    __syncthreads();
    s = ss[0] + ss[1] + ss[2] + ss[3];
    const float lse = m + __logf(s);

    for (int j = tid; j < cols; j += 256) {
        const float v = x[j] - lse;
        const float p = __expf(v);
        if (b < 128) {
            out4[(size_t)row * N + j] = v;
            pET[(size_t)j * S + row] = (__bf16)p;
        } else if (b < 256) {
            __bf16 hi, lo; split_bf16(p, hi, lo);
            Rhi[(size_t)row * S + j] = hi; Rlo[(size_t)row * S + j] = lo;
            Thi[(size_t)j * S + row] = hi; Tlo[(size_t)j * S + row] = lo;
        } else {
            out3[((size_t)0 * C + row) * S + j] = v;
            __bf16 hi, lo; split_bf16(p, hi, lo);
            Hhi[(size_t)row * S + j] = hi; Hlo[(size_t)row * S + j] = lo;
        }
    }
}

// ---------------------------------------------------------------------------
// MEGA kernel v6: H-doubling rounds + observation GEMM fused in ONE launch
// with device-scope flag dependencies. Replaces 9 round launches + 1 obs
// launch (theory: remaining time is launch/serialization latency, not BW —
// two store-path changes each moved only ~-6 us).
//
//  - 512 blocks x 512 threads (<=2 blocks/CU; >=256 co-resident guaranteed).
//  - role ticket (sync_[10]): first 256 takers run the unrolled 9-round
//    ladder with flag barriers in sync_[1..9] (RELEASE add / ACQUIRE spin,
//    agent scope -> correct across non-coherent XCD L2s).
//  - all blocks then pull obs tiles from ticket sync_[11]; tile (bx,by)
//    waits only for round ceil(log2(8*(by+1))) -> obs overlaps the ladder.
//  - round participants(r) = count(r) + (r<9 ? 8 : 0)  [H-blocks + R-sq].
//  - deadlock-free for ANY dispatch order: producers are the first 256
//    blocks that actually execute; >=256 blocks always resident.
// ---------------------------------------------------------------------------
__global__ __launch_bounds__(512, 4) void mega_kernel(
        __bf16* Pa0, __bf16* Pa1, __bf16* Pa2, __bf16* Pa3,   // slot 0 planes
        __bf16* Pb0, __bf16* Pb1, __bf16* Pb2, __bf16* Pb3,   // slot 1 planes
        __bf16* __restrict__ Hhi, __bf16* __restrict__ Hlo,
        float* __restrict__ out3,
        const __bf16* __restrict__ pET, const float* __restrict__ pcw,
        float* __restrict__ out1, float* __restrict__ out2,
        unsigned* sync_) {
    constexpr int RB = 256;          // round-role count
    constexpr unsigned NTILE = 2048; // obs tiles: 32 x-blocks * 64 y-blocks
    constexpr int BPITCH = 264;      // LDS row pitch (256 data + 8 pad)
    __shared__ __align__(16) unsigned char Bs[128 * BPITCH];  // 33 KB
    __shared__ float sw[8][C];
    __shared__ unsigned sTile;

    const int tid = threadIdx.x;

    // ---- role assignment ----
    if (tid == 0)
        sTile = __hip_atomic_fetch_add(&sync_[10], 1u, __ATOMIC_RELAXED,
                                       __HIP_MEMORY_SCOPE_AGENT);
    __syncthreads();
    const unsigned role = sTile;

    if (role < RB) {
        // =================== round ladder (9 rounds, unrolled) ===========
        const int w = (tid >> 6) & 3;
        const int lane = tid & 63;
        const int lr = lane & 15;
        const int quad = lane >> 4;
#pragma unroll
        for (int r = 1; r <= 9; ++r) {
            const int m = 1 << (r - 1);
            const int count = (m < T - m) ? m : (T - m);
            if (r >= 2) {
                const int pm = 1 << (r - 2);
                const int pcount = (pm < T - pm) ? pm : (T - pm);
                const unsigned need = (unsigned)(pcount + 8);   // r-1 <= 8 always
                if (tid == 0) {
                    while (__hip_atomic_load(&sync_[r - 1], __ATOMIC_ACQUIRE,
                                             __HIP_MEMORY_SCOPE_AGENT) < need)
                        __builtin_amdgcn_s_sleep(1);
                }
                __syncthreads();
            }
            // src slot s = (r-1)&1, dst slot d = r&1 (compile-time after unroll)
            __bf16* RhiS = ((r - 1) & 1) ? Pb0 : Pa0;
            __bf16* RloS = ((r - 1) & 1) ? Pb1 : Pa1;
            __bf16* ThiS = ((r - 1) & 1) ? Pb2 : Pa2;
            __bf16* TloS = ((r - 1) & 1) ? Pb3 : Pa3;
            __bf16* RhiD = (r & 1) ? Pb0 : Pa0;
            __bf16* RloD = (r & 1) ? Pb1 : Pa1;
            __bf16* ThiD = (r & 1) ? Pb2 : Pa2;
            __bf16* TloD = (r & 1) ? Pb3 : Pa3;

            bool part = false;
            if ((int)role < count) {
                part = true;
                if (tid < 256) {
                    const __bf16* Ahi = Hhi + (size_t)role * C * S;
                    const __bf16* Alo = Hlo + (size_t)role * C * S;
                    floatx4 acc[2][2];
#pragma unroll
                    for (int mt = 0; mt < 2; mt++)
#pragma unroll
                        for (int nt = 0; nt < 2; nt++) acc[mt][nt] = (floatx4)0.f;
#pragma unroll
                    for (int kt = 0; kt < 4; kt++) {
                        const int ko = kt * 32 + quad * 8;
                        const bf16x8 ah0 = *reinterpret_cast<const bf16x8*>(&Ahi[(size_t)lr * S + ko]);
                        const bf16x8 ah1 = *reinterpret_cast<const bf16x8*>(&Ahi[(size_t)(16 + lr) * S + ko]);
                        const bf16x8 al0 = *reinterpret_cast<const bf16x8*>(&Alo[(size_t)lr * S + ko]);
                        const bf16x8 al1 = *reinterpret_cast<const bf16x8*>(&Alo[(size_t)(16 + lr) * S + ko]);
                        const bf16x8 bh0 = *reinterpret_cast<const bf16x8*>(&ThiS[(size_t)(w * 32 + lr) * S + ko]);
                        const bf16x8 bh1 = *reinterpret_cast<const bf16x8*>(&ThiS[(size_t)(w * 32 + 16 + lr) * S + ko]);
                        const bf16x8 bl0 = *reinterpret_cast<const bf16x8*>(&TloS[(size_t)(w * 32 + lr) * S + ko]);
                        const bf16x8 bl1 = *reinterpret_cast<const bf16x8*>(&TloS[(size_t)(w * 32 + 16 + lr) * S + ko]);
                        acc[0][0] = __builtin_amdgcn_mfma_f32_16x16x32_bf16(ah0, bh0, acc[0][0], 0, 0, 0);
                        acc[0][0] = __builtin_amdgcn_mfma_f32_16x16x32_bf16(ah0, bl0, acc[0][0], 0, 0, 0);
                        acc[0][0] = __builtin_amdgcn_mfma_f32_16x16x32_bf16(al0, bh0, acc[0][0], 0, 0, 0);
                        acc[0][1] = __builtin_amdgcn_mfma_f32_16x16x32_bf16(ah0, bh1, acc[0][1], 0, 0, 0);
                        acc[0][1] = __builtin_amdgcn_mfma_f32_16x16x32_bf16(ah0, bl1, acc[0][1], 0, 0, 0);
                        acc[0][1] = __builtin_amdgcn_mfma_f32_16x16x32_bf16(al0, bh1, acc[0][1], 0, 0, 0);
                        acc[1][0] = __builtin_amdgcn_mfma_f32_16x16x32_bf16(ah1, bh0, acc[1][0], 0, 0, 0);
                        acc[1][0] = __builtin_amdgcn_mfma_f32_16x16x32_bf16(ah1, bl0, acc[1][0], 0, 0, 0);
                        acc[1][0] = __builtin_amdgcn_mfma_f32_16x16x32_bf16(al1, bh0, acc[1][0], 0, 0, 0);
                        acc[1][1] = __builtin_amdgcn_mfma_f32_16x16x32_bf16(ah1, bh1, acc[1][1], 0, 0, 0);
                        acc[1][1] = __builtin_amdgcn_mfma_f32_16x16x32_bf16(ah1, bl1, acc[1][1], 0, 0, 0);
                        acc[1][1] = __builtin_amdgcn_mfma_f32_16x16x32_bf16(al1, bh1, acc[1][1], 0, 0, 0);
                    }
                    const size_t t = (size_t)m + role;
#pragma unroll
                    for (int mt = 0; mt < 2; mt++) {
#pragma unroll
                        for (int nt = 0; nt < 2; nt++) {
#pragma unroll
                            for (int reg = 0; reg < 4; reg++) {
                                const int c = mt * 16 + quad * 4 + reg;
                                const int n = w * 32 + nt * 16 + lr;
                                const float p = acc[mt][nt][reg];
                                __bf16 hi, lo; split_bf16(p, hi, lo);
                                Hhi[(t * C + c) * S + n] = hi;
                                Hlo[(t * C + c) * S + n] = lo;
                                out3[(t * C + c) * S + n] = __logf(p);
                            }
                        }
                    }
                }
            } else if (r < 9 && (int)role < count + 8) {
                part = true;
                if (tid < 256) {
                    const int rb = (int)role - count;
                    floatx4 acc[2];
                    acc[0] = (floatx4)0.f; acc[1] = (floatx4)0.f;
#pragma unroll
                    for (int kt = 0; kt < 4; kt++) {
                        const int ko = kt * 32 + quad * 8;
                        const bf16x8 ah = *reinterpret_cast<const bf16x8*>(&RhiS[(size_t)(rb * 16 + lr) * S + ko]);
                        const bf16x8 al = *reinterpret_cast<const bf16x8*>(&RloS[(size_t)(rb * 16 + lr) * S + ko]);
                        const bf16x8 bh0 = *reinterpret_cast<const bf16x8*>(&ThiS[(size_t)(w * 32 + lr) * S + ko]);
                        const bf16x8 bh1 = *reinterpret_cast<const bf16x8*>(&ThiS[(size_t)(w * 32 + 16 + lr) * S + ko]);
                        const bf16x8 bl0 = *reinterpret_cast<const bf16x8*>(&TloS[(size_t)(w * 32 + lr) * S + ko]);
                        const bf16x8 bl1 = *reinterpret_cast<const bf16x8*>(&TloS[(size_t)(w * 32 + 16 + lr) * S + ko]);
                        acc[0] = __builtin_amdgcn_mfma_f32_16x16x32_bf16(ah, bh0, acc[0], 0, 0, 0);
                        acc[0] = __builtin_amdgcn_mfma_f32_16x16x32_bf16(ah, bl0, acc[0], 0, 0, 0);
                        acc[0] = __builtin_amdgcn_mfma_f32_16x16x32_bf16(al, bh0, acc[0], 0, 0, 0);
                        acc[1] = __builtin_amdgcn_mfma_f32_16x16x32_bf16(ah, bh1, acc[1], 0, 0, 0);
                        acc[1] = __builtin_amdgcn_mfma_f32_16x16x32_bf16(ah, bl1, acc[1], 0, 0, 0);
                        acc[1] = __builtin_amdgcn_mfma_f32_16x16x32_bf16(al, bh1, acc[1], 0, 0, 0);
                    }
#pragma unroll
                    for (int nt = 0; nt < 2; nt++) {
#pragma unroll
                        for (int reg = 0; reg < 4; reg++) {
                            const int row = rb * 16 + quad * 4 + reg;
                            const int col = w * 32 + nt * 16 + lr;
                            const float p = acc[nt][reg];
                            __bf16 hi, lo; split_bf16(p, hi, lo);
                            RhiD[(size_t)row * S + col] = hi; RloD[(size_t)row * S + col] = lo;
                            ThiD[(size_t)col * S + row] = hi; TloD[(size_t)col * S + row] = lo;
                        }
                    }
                }
            }
            __syncthreads();   // drain this block's writes (vmcnt 0 at barrier)
            if (part && tid == 0)
                __hip_atomic_fetch_add(&sync_[r], 1u, __ATOMIC_RELEASE,
                                       __HIP_MEMORY_SCOPE_AGENT);
        }
    }

    // =================== obs tile consumer (all blocks) ==================
    const int w8 = tid >> 6;       // wave id 0..7 -> t offset within tile
    const int lane = tid & 63;
    const int l31 = lane & 31;
    const int half = lane >> 5;

    for (;;) {
        if (tid == 0)
            sTile = __hip_atomic_fetch_add(&sync_[11], 1u, __ATOMIC_RELAXED,
                                           __HIP_MEMORY_SCOPE_AGENT);
        __syncthreads();           // also separates LDS reuse across tiles
        const unsigned my = sTile;
        if (my >= NTILE) break;
        const int bx = (int)(my & 31);
        const int by = (int)(my >> 5);
        const int nblk = bx * 128;
        const int tbase = by * 8;

        // readiness: tile needs H[t] final for t < 8*(by+1) -> round 3+ceil(log2(by+1))
        int k = 0;
        while ((1 << k) < by + 1) ++k;
        const int rn = 3 + k;
        const int mm = 1 << (rn - 1);
        const int cc = (mm < T - mm) ? mm : (T - mm);
        const unsigned need = (unsigned)(cc + (rn < 9 ? 8 : 0));
        if (tid == 0) {
            while (__hip_atomic_load(&sync_[rn], __ATOMIC_ACQUIRE,
                                     __HIP_MEMORY_SCOPE_AGENT) < need)
                __builtin_amdgcn_s_sleep(16);
        }
        __syncthreads();

        // ---- stage pET rows [nblk, nblk+128) into LDS ----
#pragma unroll
        for (int p = 0; p < 4; p++) {
            const int idx = p * 512 + tid;     // 0..2047
            const int row = idx >> 4;          // 0..127
            const int c16 = idx & 15;          // 16B chunk within row
            const float4 v = *reinterpret_cast<const float4*>(
                pET + (size_t)(nblk + row) * S + c16 * 8);
            *reinterpret_cast<float4*>(Bs + row * BPITCH + c16 * 16) = v;
        }
        if (tid < 256) sw[tid >> 5][tid & 31] =
            pcw[(size_t)(tbase + (tid >> 5)) * C + (tid & 31)];
        __syncthreads();

        const int t = tbase + w8;
        const __bf16* A = Hhi + (size_t)t * C * S;

        floatx16 acc[4];
#pragma unroll
        for (int nt = 0; nt < 4; nt++) acc[nt] = (floatx16)0.f;

#pragma unroll
        for (int ks = 0; ks < 8; ks++) {
            const int ko = ks * 16 + half * 8;
            const bf16x8 a  = *reinterpret_cast<const bf16x8*>(&A[(size_t)l31 * S + ko]);
            const bf16x8 b0 = *reinterpret_cast<const bf16x8*>(Bs + (l31) * BPITCH + ko * 2);
            const bf16x8 b1 = *reinterpret_cast<const bf16x8*>(Bs + (32 + l31) * BPITCH + ko * 2);
            const bf16x8 b2 = *reinterpret_cast<const bf16x8*>(Bs + (64 + l31) * BPITCH + ko * 2);
            const bf16x8 b3 = *reinterpret_cast<const bf16x8*>(Bs + (96 + l31) * BPITCH + ko * 2);
            acc[0] = __builtin_amdgcn_mfma_f32_32x32x16_bf16(a, b0, acc[0], 0, 0, 0);
            acc[1] = __builtin_amdgcn_mfma_f32_32x32x16_bf16(a, b1, acc[1], 0, 0, 0);
            acc[2] = __builtin_amdgcn_mfma_f32_32x32x16_bf16(a, b2, acc[2], 0, 0, 0);
            acc[3] = __builtin_amdgcn_mfma_f32_32x32x16_bf16(a, b3, acc[3], 0, 0, 0);
        }

        float p0 = 0.f, p1 = 0.f, p2 = 0.f, p3 = 0.f;
#pragma unroll
        for (int reg = 0; reg < 16; reg++) {
            const int c = (reg & 3) + 8 * (reg >> 2) + 4 * half;
            const float wv = sw[w8][c];
            const float o0 = acc[0][reg];
            const float o1 = acc[1][reg];
            const float o2 = acc[2][reg];
            const float o3 = acc[3][reg];
            float* rowp = &out2[((size_t)t * C + c) * N + nblk + l31];
            rowp[0]  = __logf(o0);
            rowp[32] = __logf(o1);
            rowp[64] = __logf(o2);
            rowp[96] = __logf(o3);
            p0 = fmaf(wv, o0, p0);
            p1 = fmaf(wv, o1, p1);
            p2 = fmaf(wv, o2, p2);
            p3 = fmaf(wv, o3, p3);
        }
        p0 += __shfl_xor(p0, 32, 64);
        p1 += __shfl_xor(p1, 32, 64);
        p2 += __shfl_xor(p2, 32, 64);
        p3 += __shfl_xor(p3, 32, 64);
        if (half == 0) {
            float* o1p = &out1[(size_t)t * N + nblk + l31];
            o1p[0]  = __logf(p0);
            o1p[32] = __logf(p1);
            o1p[64] = __logf(p2);
            o1p[96] = __logf(p3);
        }
    }
}

// ---------------------------------------------------------------------------
extern "C" void kernel_launch(void* const* d_in, const int* in_sizes, int n_in,
                              void* d_out, int out_size, void* d_ws, size_t ws_size,
                              hipStream_t stream) {
    const float* in_init  = (const float*)d_in[0];  // [C,S]
    const float* in_cw    = (const float*)d_in[1];  // [T,C]
    const float* in_emis  = (const float*)d_in[2];  // [S,N]
    const float* in_trans = (const float*)d_in[3];  // [S,S]

    float* out = (float*)d_out;

    // Workspace layout (~9.4 MB + 48 B sync, 256B aligned)
    char* wsb = (char*)d_ws;
    float*  ws_pcw = (float*)(wsb);                                  // 64 KB [T,C]
    __bf16* ws_pET = (__bf16*)(wsb + (64u << 10));                   // 1 MB  [N,S]
    __bf16* ws_Hhi = (__bf16*)(wsb + (1088u << 10));                 // 4 MB  [T,C,S]
    __bf16* ws_Hlo = (__bf16*)(wsb + (5184u << 10));                 // 4 MB  [T,C,S]
    __bf16* Pslot[2][4];
    for (int sl = 0; sl < 2; sl++)
        for (int pl = 0; pl < 4; pl++)
            Pslot[sl][pl] = (__bf16*)(wsb + (9280u << 10) + (size_t)(sl * 4 + pl) * (32u << 10));
    unsigned* ws_sync = (unsigned*)(wsb + (9536u << 10));            // 12 words

    // 1) All softmaxes in one launch (+ flag zeroing).
    fused_softmax_kernel<<<352, 256, 0, stream>>>(
        in_emis, in_cw, in_trans, in_init,
        out + OFF3, out + OFF4, out + OFF5,
        ws_pET, ws_pcw,
        Pslot[0][0], Pslot[0][1], Pslot[0][2], Pslot[0][3],
        ws_Hhi, ws_Hlo, ws_sync);

    // 2) Mega kernel: rounds + obs fused, flag-based dependencies.
    mega_kernel<<<512, 512, 0, stream>>>(
        Pslot[0][0], Pslot[0][1], Pslot[0][2], Pslot[0][3],
        Pslot[1][0], Pslot[1][1], Pslot[1][2], Pslot[1][3],
        ws_Hhi, ws_Hlo, out + OFF3,
        ws_pET, ws_pcw, out + OFF1, out + OFF2,
        ws_sync);
}

// Round 5
// 647.097 us; speedup vs baseline: 1.2936x; 1.2936x over previous
//
#include <hip/hip_runtime.h>
#include <hip/hip_bf16.h>
#include <cmath>

// Problem constants (fixed by setup_inputs)
constexpr int S = 128;   // num_states
constexpr int C = 32;    // num_chains
constexpr int N = 4096;  // num_nodes
constexpr int T = 512;   // num_iters

// Output layout (flat float32, concatenated in reference return order)
constexpr size_t OFF1 = 0;                          // log_observed_state_probs  [T,N]
constexpr size_t OFF2 = OFF1 + (size_t)T * N;       // log_observed_state_probs_ [T,C,N]
constexpr size_t OFF3 = OFF2 + (size_t)T * C * N;   // log_hidden_state_probs   [T,C,S]
constexpr size_t OFF4 = OFF3 + (size_t)T * C * S;   // log_emission             [S,N]
constexpr size_t OFF5 = OFF4 + (size_t)S * N;       // log_chain_weights        [T,C]

typedef __bf16 bf16x8 __attribute__((ext_vector_type(8)));
typedef float floatx4 __attribute__((ext_vector_type(4)));
typedef float floatx16 __attribute__((ext_vector_type(16)));

__device__ __forceinline__ void split_bf16(float p, __bf16& hi, __bf16& lo) {
    hi = (__bf16)p;
    lo = (__bf16)(p - (float)hi);
}

// ---------------------------------------------------------------------------
// Fused softmax kernel, one launch, 352 blocks x 256 threads (v5 form).
// ---------------------------------------------------------------------------
__global__ __launch_bounds__(256) void fused_softmax_kernel(
        const float* __restrict__ emis, const float* __restrict__ cw,
        const float* __restrict__ trans, const float* __restrict__ init,
        float* __restrict__ out3, float* __restrict__ out4, float* __restrict__ out5,
        __bf16* __restrict__ pET, float* __restrict__ pcw,
        __bf16* __restrict__ Rhi, __bf16* __restrict__ Rlo,
        __bf16* __restrict__ Thi, __bf16* __restrict__ Tlo,
        __bf16* __restrict__ Hhi, __bf16* __restrict__ Hlo) {
    const int b = blockIdx.x;
    const int tid = threadIdx.x;

    if (b >= 288) {   // ---- chain weights: 8 rows of 32 per block ----
        const int row = (b - 288) * 8 + (tid >> 5);
        const int j = tid & 31;
        const float v = cw[(size_t)row * C + j];
        float m = v;
#pragma unroll
        for (int o = 16; o > 0; o >>= 1) m = fmaxf(m, __shfl_xor(m, o, 64));
        float s = __expf(v - m);
#pragma unroll
        for (int o = 16; o > 0; o >>= 1) s += __shfl_xor(s, o, 64);
        const float lv = v - m - __logf(s);
        out5[(size_t)row * C + j] = lv;
        pcw[(size_t)row * C + j] = __expf(lv);
        return;
    }

    const float* x;
    int cols, row;
    if (b < 128)      { row = b;       cols = N; x = emis  + (size_t)row * N; }
    else if (b < 256) { row = b - 128; cols = S; x = trans + (size_t)row * S; }
    else              { row = b - 256; cols = S; x = init  + (size_t)row * S; }

    __shared__ float sm[4];
    __shared__ float ss[4];

    float m = -INFINITY;
    for (int j = tid; j < cols; j += 256) m = fmaxf(m, x[j]);
#pragma unroll
    for (int o = 32; o > 0; o >>= 1) m = fmaxf(m, __shfl_xor(m, o, 64));
    const int wid = tid >> 6;
    if ((tid & 63) == 0) sm[wid] = m;
    __syncthreads();
    m = fmaxf(fmaxf(sm[0], sm[1]), fmaxf(sm[2], sm[3]));

    float s = 0.f;
    for (int j = tid; j < cols; j += 256) s += __expf(x[j] - m);
#pragma unroll
    for (int o = 32; o > 0; o >>= 1) s += __shfl_xor(s, o, 64);
    if ((tid & 63) == 0) ss[wid] = s;
    __syncthreads();
    s = ss[0] + ss[1] + ss[2] + ss[3];
    const float lse = m + __logf(s);

    for (int j = tid; j < cols; j += 256) {
        const float v = x[j] - lse;
        const float p = __expf(v);
        if (b < 128) {
            out4[(size_t)row * N + j] = v;
            pET[(size_t)j * S + row] = (__bf16)p;
        } else if (b < 256) {
            __bf16 hi, lo; split_bf16(p, hi, lo);
            Rhi[(size_t)row * S + j] = hi; Rlo[(size_t)row * S + j] = lo;
            Thi[(size_t)j * S + row] = hi; Tlo[(size_t)j * S + row] = lo;
        } else {
            out3[((size_t)0 * C + row) * S + j] = v;
            __bf16 hi, lo; split_bf16(p, hi, lo);
            Hhi[(size_t)row * S + j] = hi; Hlo[(size_t)row * S + j] = lo;
        }
    }
}

// ---------------------------------------------------------------------------
// H-body for one (t, col-wave) unit — identical arithmetic to v5's
// h_round_kernel H-branch.
// ---------------------------------------------------------------------------
__device__ __forceinline__ void h_unit(
        int b, int w, int m, int lr, int quad,
        const __bf16* ThiS, const __bf16* TloS,
        __bf16* Hhi, __bf16* Hlo, float* out3) {
    const __bf16* Ahi = Hhi + (size_t)b * C * S;
    const __bf16* Alo = Hlo + (size_t)b * C * S;
    floatx4 acc[2][2];
#pragma unroll
    for (int mt = 0; mt < 2; mt++)
#pragma unroll
        for (int nt = 0; nt < 2; nt++) acc[mt][nt] = (floatx4)0.f;

#pragma unroll
    for (int kt = 0; kt < 4; kt++) {
        const int ko = kt * 32 + quad * 8;
        const bf16x8 ah0 = *reinterpret_cast<const bf16x8*>(&Ahi[(size_t)lr * S + ko]);
        const bf16x8 ah1 = *reinterpret_cast<const bf16x8*>(&Ahi[(size_t)(16 + lr) * S + ko]);
        const bf16x8 al0 = *reinterpret_cast<const bf16x8*>(&Alo[(size_t)lr * S + ko]);
        const bf16x8 al1 = *reinterpret_cast<const bf16x8*>(&Alo[(size_t)(16 + lr) * S + ko]);
        const bf16x8 bh0 = *reinterpret_cast<const bf16x8*>(&ThiS[(size_t)(w * 32 + lr) * S + ko]);
        const bf16x8 bh1 = *reinterpret_cast<const bf16x8*>(&ThiS[(size_t)(w * 32 + 16 + lr) * S + ko]);
        const bf16x8 bl0 = *reinterpret_cast<const bf16x8*>(&TloS[(size_t)(w * 32 + lr) * S + ko]);
        const bf16x8 bl1 = *reinterpret_cast<const bf16x8*>(&TloS[(size_t)(w * 32 + 16 + lr) * S + ko]);
        acc[0][0] = __builtin_amdgcn_mfma_f32_16x16x32_bf16(ah0, bh0, acc[0][0], 0, 0, 0);
        acc[0][0] = __builtin_amdgcn_mfma_f32_16x16x32_bf16(ah0, bl0, acc[0][0], 0, 0, 0);
        acc[0][0] = __builtin_amdgcn_mfma_f32_16x16x32_bf16(al0, bh0, acc[0][0], 0, 0, 0);
        acc[0][1] = __builtin_amdgcn_mfma_f32_16x16x32_bf16(ah0, bh1, acc[0][1], 0, 0, 0);
        acc[0][1] = __builtin_amdgcn_mfma_f32_16x16x32_bf16(ah0, bl1, acc[0][1], 0, 0, 0);
        acc[0][1] = __builtin_amdgcn_mfma_f32_16x16x32_bf16(al0, bh1, acc[0][1], 0, 0, 0);
        acc[1][0] = __builtin_amdgcn_mfma_f32_16x16x32_bf16(ah1, bh0, acc[1][0], 0, 0, 0);
        acc[1][0] = __builtin_amdgcn_mfma_f32_16x16x32_bf16(ah1, bl0, acc[1][0], 0, 0, 0);
        acc[1][0] = __builtin_amdgcn_mfma_f32_16x16x32_bf16(al1, bh0, acc[1][0], 0, 0, 0);
        acc[1][1] = __builtin_amdgcn_mfma_f32_16x16x32_bf16(ah1, bh1, acc[1][1], 0, 0, 0);
        acc[1][1] = __builtin_amdgcn_mfma_f32_16x16x32_bf16(ah1, bl1, acc[1][1], 0, 0, 0);
        acc[1][1] = __builtin_amdgcn_mfma_f32_16x16x32_bf16(al1, bh1, acc[1][1], 0, 0, 0);
    }

    const size_t t = (size_t)m + b;
#pragma unroll
    for (int mt = 0; mt < 2; mt++) {
#pragma unroll
        for (int nt = 0; nt < 2; nt++) {
#pragma unroll
            for (int reg = 0; reg < 4; reg++) {
                const int c = mt * 16 + quad * 4 + reg;
                const int n = w * 32 + nt * 16 + lr;
                const float p = acc[mt][nt][reg];
                __bf16 hi, lo; split_bf16(p, hi, lo);
                Hhi[(t * C + c) * S + n] = hi;
                Hlo[(t * C + c) * S + n] = lo;
                out3[(t * C + c) * S + n] = __logf(p);
            }
        }
    }
}

// R-squaring body for one (row-block, col-wave) unit — identical to v5.
__device__ __forceinline__ void r_unit(
        int rb, int w, int lr, int quad,
        const __bf16* RhiS, const __bf16* RloS,
        const __bf16* ThiS, const __bf16* TloS,
        __bf16* RhiD, __bf16* RloD, __bf16* ThiD, __bf16* TloD) {
    floatx4 acc[2];
    acc[0] = (floatx4)0.f; acc[1] = (floatx4)0.f;
#pragma unroll
    for (int kt = 0; kt < 4; kt++) {
        const int ko = kt * 32 + quad * 8;
        const bf16x8 ah = *reinterpret_cast<const bf16x8*>(&RhiS[(size_t)(rb * 16 + lr) * S + ko]);
        const bf16x8 al = *reinterpret_cast<const bf16x8*>(&RloS[(size_t)(rb * 16 + lr) * S + ko]);
        const bf16x8 bh0 = *reinterpret_cast<const bf16x8*>(&ThiS[(size_t)(w * 32 + lr) * S + ko]);
        const bf16x8 bh1 = *reinterpret_cast<const bf16x8*>(&ThiS[(size_t)(w * 32 + 16 + lr) * S + ko]);
        const bf16x8 bl0 = *reinterpret_cast<const bf16x8*>(&TloS[(size_t)(w * 32 + lr) * S + ko]);
        const bf16x8 bl1 = *reinterpret_cast<const bf16x8*>(&TloS[(size_t)(w * 32 + 16 + lr) * S + ko]);
        acc[0] = __builtin_amdgcn_mfma_f32_16x16x32_bf16(ah, bh0, acc[0], 0, 0, 0);
        acc[0] = __builtin_amdgcn_mfma_f32_16x16x32_bf16(ah, bl0, acc[0], 0, 0, 0);
        acc[0] = __builtin_amdgcn_mfma_f32_16x16x32_bf16(al, bh0, acc[0], 0, 0, 0);
        acc[1] = __builtin_amdgcn_mfma_f32_16x16x32_bf16(ah, bh1, acc[1], 0, 0, 0);
        acc[1] = __builtin_amdgcn_mfma_f32_16x16x32_bf16(ah, bl1, acc[1], 0, 0, 0);
        acc[1] = __builtin_amdgcn_mfma_f32_16x16x32_bf16(al, bh1, acc[1], 0, 0, 0);
    }
#pragma unroll
    for (int nt = 0; nt < 2; nt++) {
#pragma unroll
        for (int reg = 0; reg < 4; reg++) {
            const int row = rb * 16 + quad * 4 + reg;
            const int col = w * 32 + nt * 16 + lr;
            const float p = acc[nt][reg];
            __bf16 hi, lo; split_bf16(p, hi, lo);
            RhiD[(size_t)row * S + col] = hi; RloD[(size_t)row * S + col] = lo;
            ThiD[(size_t)col * S + row] = hi; TloD[(size_t)col * S + row] = lo;
        }
    }
}

// ---------------------------------------------------------------------------
// Rounds 1-5 fused in ONE 1024-thread block. Work per round r (m=2^(r-1)):
// m H-tiles (4 wave-units each) + full R-squaring (32 wave-units); max 96
// units over 16 waves. __syncthreads() is the round barrier — no global
// sync (v6 lesson: device-wide flag barriers cost 30-80 us each; intra-block
// barriers are ~free). Replaces 5 launches.
// ---------------------------------------------------------------------------
__global__ __launch_bounds__(1024, 4) void ladder15_kernel(
        __bf16* Pa0, __bf16* Pa1, __bf16* Pa2, __bf16* Pa3,
        __bf16* Pb0, __bf16* Pb1, __bf16* Pb2, __bf16* Pb3,
        __bf16* Hhi, __bf16* Hlo, float* out3) {
    const int tid = threadIdx.x;
    const int wid = tid >> 6;
    const int lane = tid & 63;
    const int lr = lane & 15;
    const int quad = lane >> 4;

#pragma unroll
    for (int r = 1; r <= 5; ++r) {
        const int m = 1 << (r - 1);
        __bf16* RhiS = ((r - 1) & 1) ? Pb0 : Pa0;
        __bf16* RloS = ((r - 1) & 1) ? Pb1 : Pa1;
        __bf16* ThiS = ((r - 1) & 1) ? Pb2 : Pa2;
        __bf16* TloS = ((r - 1) & 1) ? Pb3 : Pa3;
        __bf16* RhiD = (r & 1) ? Pb0 : Pa0;
        __bf16* RloD = (r & 1) ? Pb1 : Pa1;
        __bf16* ThiD = (r & 1) ? Pb2 : Pa2;
        __bf16* TloD = (r & 1) ? Pb3 : Pa3;

        const int total = m * 4 + 32;   // H wave-units + R wave-units
        for (int u = wid; u < total; u += 16) {
            if (u < m * 4) {
                h_unit(u >> 2, u & 3, m, lr, quad, ThiS, TloS, Hhi, Hlo, out3);
            } else {
                const int ru = u - m * 4;
                r_unit(ru >> 2, ru & 3, lr, quad,
                       RhiS, RloS, ThiS, TloS, RhiD, RloD, ThiD, TloD);
            }
        }
        __syncthreads();   // round barrier (drains this block's global writes)
    }
}

// ---------------------------------------------------------------------------
// Rounds 6-8 (unchanged v5 kernel, launched 3x).
// ---------------------------------------------------------------------------
__global__ __launch_bounds__(256) void h_round_kernel(
        const __bf16* __restrict__ Rhi, const __bf16* __restrict__ Rlo,
        const __bf16* __restrict__ Thi, const __bf16* __restrict__ Tlo,
        __bf16* __restrict__ Rnhi, __bf16* __restrict__ Rnlo,
        __bf16* __restrict__ Tnhi, __bf16* __restrict__ Tnlo,
        __bf16* __restrict__ Hhi, __bf16* __restrict__ Hlo,
        float* __restrict__ out3, int m, int count) {
    const int b = blockIdx.x;
    const int w = threadIdx.x >> 6;
    const int lane = threadIdx.x & 63;
    const int lr = lane & 15;
    const int quad = lane >> 4;

    if (b < count) {
        h_unit(b, w, m, lr, quad, Thi, Tlo, Hhi, Hlo, out3);
    } else {
        r_unit(b - count, w, lr, quad, Rhi, Rlo, Thi, Tlo, Rnhi, Rnlo, Tnhi, Tnlo);
    }
}

// ---------------------------------------------------------------------------
// Obs tile body (v5 logic, BPITCH 272 = 16B bank stride -> canonical
// conflict-free ds_read_b128 pattern; v6 PMC showed 1 bank conflict per
// read at pitch 264).
// ---------------------------------------------------------------------------
constexpr int BPITCH = 272;

__device__ __forceinline__ void obs_tile(
        int nblk, int tbase, int tid,
        unsigned char* Bs, float (*sw)[C],
        const __bf16* Hb, const __bf16* pET, const float* pcw,
        float* out1, float* out2) {
    const int w = tid >> 6;
    const int lane = tid & 63;
    const int l31 = lane & 31;
    const int half = lane >> 5;

    // Stage pET rows [nblk, nblk+128) into LDS (coalesced 16B chunks).
#pragma unroll
    for (int p = 0; p < 4; p++) {
        const int idx = p * 512 + tid;     // 0..2047
        const int row = idx >> 4;          // 0..127
        const int c16 = idx & 15;          // 16B chunk within row
        const float4 v = *reinterpret_cast<const float4*>(
            pET + (size_t)(nblk + row) * S + c16 * 8);
        *reinterpret_cast<float4*>(Bs + row * BPITCH + c16 * 16) = v;
    }
    if (tid < 256) sw[tid >> 5][tid & 31] =
        pcw[(size_t)(tbase + (tid >> 5)) * C + (tid & 31)];
    __syncthreads();

    const int t = tbase + w;
    const __bf16* A = Hb + (size_t)t * C * S;

    floatx16 acc[4];
#pragma unroll
    for (int nt = 0; nt < 4; nt++) acc[nt] = (floatx16)0.f;

#pragma unroll
    for (int ks = 0; ks < 8; ks++) {
        const int ko = ks * 16 + half * 8;
        const bf16x8 a  = *reinterpret_cast<const bf16x8*>(&A[(size_t)l31 * S + ko]);
        const bf16x8 b0 = *reinterpret_cast<const bf16x8*>(Bs + (l31) * BPITCH + ko * 2);
        const bf16x8 b1 = *reinterpret_cast<const bf16x8*>(Bs + (32 + l31) * BPITCH + ko * 2);
        const bf16x8 b2 = *reinterpret_cast<const bf16x8*>(Bs + (64 + l31) * BPITCH + ko * 2);
        const bf16x8 b3 = *reinterpret_cast<const bf16x8*>(Bs + (96 + l31) * BPITCH + ko * 2);
        acc[0] = __builtin_amdgcn_mfma_f32_32x32x16_bf16(a, b0, acc[0], 0, 0, 0);
        acc[1] = __builtin_amdgcn_mfma_f32_32x32x16_bf16(a, b1, acc[1], 0, 0, 0);
        acc[2] = __builtin_amdgcn_mfma_f32_32x32x16_bf16(a, b2, acc[2], 0, 0, 0);
        acc[3] = __builtin_amdgcn_mfma_f32_32x32x16_bf16(a, b3, acc[3], 0, 0, 0);
    }

    float p0 = 0.f, p1 = 0.f, p2 = 0.f, p3 = 0.f;
#pragma unroll
    for (int reg = 0; reg < 16; reg++) {
        const int c = (reg & 3) + 8 * (reg >> 2) + 4 * half;
        const float wv = sw[w][c];
        const float o0 = acc[0][reg];
        const float o1 = acc[1][reg];
        const float o2 = acc[2][reg];
        const float o3 = acc[3][reg];
        float* rowp = &out2[((size_t)t * C + c) * N + nblk + l31];
        rowp[0]  = __logf(o0);
        rowp[32] = __logf(o1);
        rowp[64] = __logf(o2);
        rowp[96] = __logf(o3);
        p0 = fmaf(wv, o0, p0);
        p1 = fmaf(wv, o1, p1);
        p2 = fmaf(wv, o2, p2);
        p3 = fmaf(wv, o3, p3);
    }
    p0 += __shfl_xor(p0, 32, 64);
    p1 += __shfl_xor(p1, 32, 64);
    p2 += __shfl_xor(p2, 32, 64);
    p3 += __shfl_xor(p3, 32, 64);
    if (half == 0) {
        float* o1p = &out1[(size_t)t * N + nblk + l31];
        o1p[0]  = __logf(p0);
        o1p[32] = __logf(p1);
        o1p[64] = __logf(p2);
        o1p[96] = __logf(p3);
    }
}

// ---------------------------------------------------------------------------
// Round 9 + low-t obs fused: blocks 0..255 do the r9 H-fill (t=256+b);
// blocks 256..1279 do obs tiles with t<256. Both depend only on data final
// at launch -> no synchronization of any kind. r9's ~5us hides under obs.
// ---------------------------------------------------------------------------
__global__ __launch_bounds__(512, 4) void r9_obs_kernel(
        const __bf16* __restrict__ Thi0, const __bf16* __restrict__ Tlo0,
        __bf16* __restrict__ Hhi, __bf16* __restrict__ Hlo,
        float* __restrict__ out3,
        const __bf16* __restrict__ pET, const float* __restrict__ pcw,
        float* __restrict__ out1, float* __restrict__ out2) {
    __shared__ __align__(16) unsigned char Bs[128 * BPITCH];
    __shared__ float sw[8][C];

    const int b = blockIdx.x;
    const int tid = threadIdx.x;

    if (b < 256) {
        if (tid < 256) {
            const int lane = tid & 63;
            h_unit(b, tid >> 6, 256, lane & 15, lane >> 4,
                   Thi0, Tlo0, Hhi, Hlo, out3);
        }
        return;
    }
    const int idx = b - 256;          // 0..1023
    const int nblk = (idx & 31) * 128;
    const int tbase = (idx >> 5) * 8; // t in [0, 256)
    obs_tile(nblk, tbase, tid, Bs, sw, Hhi, pET, pcw, out1, out2);
}

// High-t obs: tiles with t in [256, 512).
__global__ __launch_bounds__(512, 4) void obs_hi_kernel(
        const __bf16* __restrict__ Hb, const __bf16* __restrict__ pET,
        const float* __restrict__ pcw,
        float* __restrict__ out1, float* __restrict__ out2) {
    __shared__ __align__(16) unsigned char Bs[128 * BPITCH];
    __shared__ float sw[8][C];
    const int nblk = blockIdx.x * 128;
    const int tbase = 256 + blockIdx.y * 8;
    obs_tile(nblk, tbase, (int)threadIdx.x, Bs, sw, Hb, pET, pcw, out1, out2);
}

// ---------------------------------------------------------------------------
extern "C" void kernel_launch(void* const* d_in, const int* in_sizes, int n_in,
                              void* d_out, int out_size, void* d_ws, size_t ws_size,
                              hipStream_t stream) {
    const float* in_init  = (const float*)d_in[0];  // [C,S]
    const float* in_cw    = (const float*)d_in[1];  // [T,C]
    const float* in_emis  = (const float*)d_in[2];  // [S,N]
    const float* in_trans = (const float*)d_in[3];  // [S,S]

    float* out = (float*)d_out;

    // Workspace layout (~9.5 MB, 256B aligned)
    char* wsb = (char*)d_ws;
    float*  ws_pcw = (float*)(wsb);                                  // 64 KB [T,C]
    __bf16* ws_pET = (__bf16*)(wsb + (64u << 10));                   // 1 MB  [N,S]
    __bf16* ws_Hhi = (__bf16*)(wsb + (1088u << 10));                 // 4 MB  [T,C,S]
    __bf16* ws_Hlo = (__bf16*)(wsb + (5184u << 10));                 // 4 MB  [T,C,S]
    __bf16* Pslot[2][4];
    for (int sl = 0; sl < 2; sl++)
        for (int pl = 0; pl < 4; pl++)
            Pslot[sl][pl] = (__bf16*)(wsb + (9280u << 10) + (size_t)(sl * 4 + pl) * (32u << 10));

    // 1) All softmaxes in one launch.
    fused_softmax_kernel<<<352, 256, 0, stream>>>(
        in_emis, in_cw, in_trans, in_init,
        out + OFF3, out + OFF4, out + OFF5,
        ws_pET, ws_pcw,
        Pslot[0][0], Pslot[0][1], Pslot[0][2], Pslot[0][3],
        ws_Hhi, ws_Hlo);

    // 2) Rounds 1-5 fused in one block (slot parity preserved: round r
    //    writes slot r&1; after r=5 the R^32 planes sit in slot 1).
    ladder15_kernel<<<1, 1024, 0, stream>>>(
        Pslot[0][0], Pslot[0][1], Pslot[0][2], Pslot[0][3],
        Pslot[1][0], Pslot[1][1], Pslot[1][2], Pslot[1][3],
        ws_Hhi, ws_Hlo, out + OFF3);

    // 3) Rounds 6-8 (launch-based; proven cheaper than global sync).
    for (int r = 6; r <= 8; r++) {
        const int m = 1 << (r - 1);
        const int s = (r - 1) & 1, d = r & 1;
        h_round_kernel<<<m + 8, 256, 0, stream>>>(
            Pslot[s][0], Pslot[s][1], Pslot[s][2], Pslot[s][3],
            Pslot[d][0], Pslot[d][1], Pslot[d][2], Pslot[d][3],
            ws_Hhi, ws_Hlo, out + OFF3, m, m);
    }

    // 4) Round 9 H-fill (reads slot 0 T-planes, written by r8) + obs t<256.
    r9_obs_kernel<<<1280, 512, 0, stream>>>(
        Pslot[0][2], Pslot[0][3],
        ws_Hhi, ws_Hlo, out + OFF3,
        ws_pET, ws_pcw, out + OFF1, out + OFF2);

    // 5) Obs t in [256, 512).
    obs_hi_kernel<<<dim3(32, 32), 512, 0, stream>>>(
        ws_Hhi, ws_pET, ws_pcw, out + OFF1, out + OFF2);
}

// Round 6
// 373.388 us; speedup vs baseline: 2.2418x; 1.7330x over previous
//
#include <hip/hip_runtime.h>
#include <hip/hip_bf16.h>
#include <cmath>

// Problem constants (fixed by setup_inputs)
constexpr int S = 128;   // num_states
constexpr int C = 32;    // num_chains
constexpr int N = 4096;  // num_nodes
constexpr int T = 512;   // num_iters

// Output layout (flat float32, concatenated in reference return order)
constexpr size_t OFF1 = 0;                          // log_observed_state_probs  [T,N]
constexpr size_t OFF2 = OFF1 + (size_t)T * N;       // log_observed_state_probs_ [T,C,N]
constexpr size_t OFF3 = OFF2 + (size_t)T * C * N;   // log_hidden_state_probs   [T,C,S]
constexpr size_t OFF4 = OFF3 + (size_t)T * C * S;   // log_emission             [S,N]
constexpr size_t OFF5 = OFF4 + (size_t)S * N;       // log_chain_weights        [T,C]

typedef __bf16 bf16x8 __attribute__((ext_vector_type(8)));
typedef float floatx4 __attribute__((ext_vector_type(4)));
typedef float floatx16 __attribute__((ext_vector_type(16)));

__device__ __forceinline__ void split_bf16(float p, __bf16& hi, __bf16& lo) {
    hi = (__bf16)p;
    lo = (__bf16)(p - (float)hi);
}

// ---------------------------------------------------------------------------
// Fused softmax kernel, one launch, 352 blocks x 256 threads (v5 form).
// ---------------------------------------------------------------------------
__global__ __launch_bounds__(256) void fused_softmax_kernel(
        const float* __restrict__ emis, const float* __restrict__ cw,
        const float* __restrict__ trans, const float* __restrict__ init,
        float* __restrict__ out3, float* __restrict__ out4, float* __restrict__ out5,
        __bf16* __restrict__ pET, float* __restrict__ pcw,
        __bf16* __restrict__ Rhi, __bf16* __restrict__ Rlo,
        __bf16* __restrict__ Thi, __bf16* __restrict__ Tlo,
        __bf16* __restrict__ Hhi, __bf16* __restrict__ Hlo) {
    const int b = blockIdx.x;
    const int tid = threadIdx.x;

    if (b >= 288) {   // ---- chain weights: 8 rows of 32 per block ----
        const int row = (b - 288) * 8 + (tid >> 5);
        const int j = tid & 31;
        const float v = cw[(size_t)row * C + j];
        float m = v;
#pragma unroll
        for (int o = 16; o > 0; o >>= 1) m = fmaxf(m, __shfl_xor(m, o, 64));
        float s = __expf(v - m);
#pragma unroll
        for (int o = 16; o > 0; o >>= 1) s += __shfl_xor(s, o, 64);
        const float lv = v - m - __logf(s);
        out5[(size_t)row * C + j] = lv;
        pcw[(size_t)row * C + j] = __expf(lv);
        return;
    }

    const float* x;
    int cols, row;
    if (b < 128)      { row = b;       cols = N; x = emis  + (size_t)row * N; }
    else if (b < 256) { row = b - 128; cols = S; x = trans + (size_t)row * S; }
    else              { row = b - 256; cols = S; x = init  + (size_t)row * S; }

    __shared__ float sm[4];
    __shared__ float ss[4];

    float m = -INFINITY;
    for (int j = tid; j < cols; j += 256) m = fmaxf(m, x[j]);
#pragma unroll
    for (int o = 32; o > 0; o >>= 1) m = fmaxf(m, __shfl_xor(m, o, 64));
    const int wid = tid >> 6;
    if ((tid & 63) == 0) sm[wid] = m;
    __syncthreads();
    m = fmaxf(fmaxf(sm[0], sm[1]), fmaxf(sm[2], sm[3]));

    float s = 0.f;
    for (int j = tid; j < cols; j += 256) s += __expf(x[j] - m);
#pragma unroll
    for (int o = 32; o > 0; o >>= 1) s += __shfl_xor(s, o, 64);
    if ((tid & 63) == 0) ss[wid] = s;
    __syncthreads();
    s = ss[0] + ss[1] + ss[2] + ss[3];
    const float lse = m + __logf(s);

    for (int j = tid; j < cols; j += 256) {
        const float v = x[j] - lse;
        const float p = __expf(v);
        if (b < 128) {
            out4[(size_t)row * N + j] = v;
            pET[(size_t)j * S + row] = (__bf16)p;
        } else if (b < 256) {
            __bf16 hi, lo; split_bf16(p, hi, lo);
            Rhi[(size_t)row * S + j] = hi; Rlo[(size_t)row * S + j] = lo;
            Thi[(size_t)j * S + row] = hi; Tlo[(size_t)j * S + row] = lo;
        } else {
            out3[((size_t)0 * C + row) * S + j] = v;
            __bf16 hi, lo; split_bf16(p, hi, lo);
            Hhi[(size_t)row * S + j] = hi; Hlo[(size_t)row * S + j] = lo;
        }
    }
}

// ---------------------------------------------------------------------------
// H-body for one (t, col-wave) unit — identical arithmetic to v5.
// ---------------------------------------------------------------------------
__device__ __forceinline__ void h_unit(
        int b, int w, int m, int lr, int quad,
        const __bf16* ThiS, const __bf16* TloS,
        __bf16* Hhi, __bf16* Hlo, float* out3) {
    const __bf16* Ahi = Hhi + (size_t)b * C * S;
    const __bf16* Alo = Hlo + (size_t)b * C * S;
    floatx4 acc[2][2];
#pragma unroll
    for (int mt = 0; mt < 2; mt++)
#pragma unroll
        for (int nt = 0; nt < 2; nt++) acc[mt][nt] = (floatx4)0.f;

#pragma unroll
    for (int kt = 0; kt < 4; kt++) {
        const int ko = kt * 32 + quad * 8;
        const bf16x8 ah0 = *reinterpret_cast<const bf16x8*>(&Ahi[(size_t)lr * S + ko]);
        const bf16x8 ah1 = *reinterpret_cast<const bf16x8*>(&Ahi[(size_t)(16 + lr) * S + ko]);
        const bf16x8 al0 = *reinterpret_cast<const bf16x8*>(&Alo[(size_t)lr * S + ko]);
        const bf16x8 al1 = *reinterpret_cast<const bf16x8*>(&Alo[(size_t)(16 + lr) * S + ko]);
        const bf16x8 bh0 = *reinterpret_cast<const bf16x8*>(&ThiS[(size_t)(w * 32 + lr) * S + ko]);
        const bf16x8 bh1 = *reinterpret_cast<const bf16x8*>(&ThiS[(size_t)(w * 32 + 16 + lr) * S + ko]);
        const bf16x8 bl0 = *reinterpret_cast<const bf16x8*>(&TloS[(size_t)(w * 32 + lr) * S + ko]);
        const bf16x8 bl1 = *reinterpret_cast<const bf16x8*>(&TloS[(size_t)(w * 32 + 16 + lr) * S + ko]);
        acc[0][0] = __builtin_amdgcn_mfma_f32_16x16x32_bf16(ah0, bh0, acc[0][0], 0, 0, 0);
        acc[0][0] = __builtin_amdgcn_mfma_f32_16x16x32_bf16(ah0, bl0, acc[0][0], 0, 0, 0);
        acc[0][0] = __builtin_amdgcn_mfma_f32_16x16x32_bf16(al0, bh0, acc[0][0], 0, 0, 0);
        acc[0][1] = __builtin_amdgcn_mfma_f32_16x16x32_bf16(ah0, bh1, acc[0][1], 0, 0, 0);
        acc[0][1] = __builtin_amdgcn_mfma_f32_16x16x32_bf16(ah0, bl1, acc[0][1], 0, 0, 0);
        acc[0][1] = __builtin_amdgcn_mfma_f32_16x16x32_bf16(al0, bh1, acc[0][1], 0, 0, 0);
        acc[1][0] = __builtin_amdgcn_mfma_f32_16x16x32_bf16(ah1, bh0, acc[1][0], 0, 0, 0);
        acc[1][0] = __builtin_amdgcn_mfma_f32_16x16x32_bf16(ah1, bl0, acc[1][0], 0, 0, 0);
        acc[1][0] = __builtin_amdgcn_mfma_f32_16x16x32_bf16(al1, bh0, acc[1][0], 0, 0, 0);
        acc[1][1] = __builtin_amdgcn_mfma_f32_16x16x32_bf16(ah1, bh1, acc[1][1], 0, 0, 0);
        acc[1][1] = __builtin_amdgcn_mfma_f32_16x16x32_bf16(ah1, bl1, acc[1][1], 0, 0, 0);
        acc[1][1] = __builtin_amdgcn_mfma_f32_16x16x32_bf16(al1, bh1, acc[1][1], 0, 0, 0);
    }

    const size_t t = (size_t)m + b;
#pragma unroll
    for (int mt = 0; mt < 2; mt++) {
#pragma unroll
        for (int nt = 0; nt < 2; nt++) {
#pragma unroll
            for (int reg = 0; reg < 4; reg++) {
                const int c = mt * 16 + quad * 4 + reg;
                const int n = w * 32 + nt * 16 + lr;
                const float p = acc[mt][nt][reg];
                __bf16 hi, lo; split_bf16(p, hi, lo);
                Hhi[(t * C + c) * S + n] = hi;
                Hlo[(t * C + c) * S + n] = lo;
                out3[(t * C + c) * S + n] = __logf(p);
            }
        }
    }
}

// R-squaring body for one (row-block, col-wave) unit — identical to v5.
__device__ __forceinline__ void r_unit(
        int rb, int w, int lr, int quad,
        const __bf16* RhiS, const __bf16* RloS,
        const __bf16* ThiS, const __bf16* TloS,
        __bf16* RhiD, __bf16* RloD, __bf16* ThiD, __bf16* TloD) {
    floatx4 acc[2];
    acc[0] = (floatx4)0.f; acc[1] = (floatx4)0.f;
#pragma unroll
    for (int kt = 0; kt < 4; kt++) {
        const int ko = kt * 32 + quad * 8;
        const bf16x8 ah = *reinterpret_cast<const bf16x8*>(&RhiS[(size_t)(rb * 16 + lr) * S + ko]);
        const bf16x8 al = *reinterpret_cast<const bf16x8*>(&RloS[(size_t)(rb * 16 + lr) * S + ko]);
        const bf16x8 bh0 = *reinterpret_cast<const bf16x8*>(&ThiS[(size_t)(w * 32 + lr) * S + ko]);
        const bf16x8 bh1 = *reinterpret_cast<const bf16x8*>(&ThiS[(size_t)(w * 32 + 16 + lr) * S + ko]);
        const bf16x8 bl0 = *reinterpret_cast<const bf16x8*>(&TloS[(size_t)(w * 32 + lr) * S + ko]);
        const bf16x8 bl1 = *reinterpret_cast<const bf16x8*>(&TloS[(size_t)(w * 32 + 16 + lr) * S + ko]);
        acc[0] = __builtin_amdgcn_mfma_f32_16x16x32_bf16(ah, bh0, acc[0], 0, 0, 0);
        acc[0] = __builtin_amdgcn_mfma_f32_16x16x32_bf16(ah, bl0, acc[0], 0, 0, 0);
        acc[0] = __builtin_amdgcn_mfma_f32_16x16x32_bf16(al, bh0, acc[0], 0, 0, 0);
        acc[1] = __builtin_amdgcn_mfma_f32_16x16x32_bf16(ah, bh1, acc[1], 0, 0, 0);
        acc[1] = __builtin_amdgcn_mfma_f32_16x16x32_bf16(ah, bl1, acc[1], 0, 0, 0);
        acc[1] = __builtin_amdgcn_mfma_f32_16x16x32_bf16(al, bh1, acc[1], 0, 0, 0);
    }
#pragma unroll
    for (int nt = 0; nt < 2; nt++) {
#pragma unroll
        for (int reg = 0; reg < 4; reg++) {
            const int row = rb * 16 + quad * 4 + reg;
            const int col = w * 32 + nt * 16 + lr;
            const float p = acc[nt][reg];
            __bf16 hi, lo; split_bf16(p, hi, lo);
            RhiD[(size_t)row * S + col] = hi; RloD[(size_t)row * S + col] = lo;
            ThiD[(size_t)col * S + row] = hi; TloD[(size_t)col * S + row] = lo;
        }
    }
}

// ---------------------------------------------------------------------------
// One H-doubling round (v5-proven launch structure: ~42 us for all 9; the
// v6 flag-sync variant was 850 us and the v7 single-block variant 313 us —
// per-round launches are the measured optimum for this serial ladder).
// ---------------------------------------------------------------------------
__global__ __launch_bounds__(256) void h_round_kernel(
        const __bf16* __restrict__ Rhi, const __bf16* __restrict__ Rlo,
        const __bf16* __restrict__ Thi, const __bf16* __restrict__ Tlo,
        __bf16* __restrict__ Rnhi, __bf16* __restrict__ Rnlo,
        __bf16* __restrict__ Tnhi, __bf16* __restrict__ Tnlo,
        __bf16* __restrict__ Hhi, __bf16* __restrict__ Hlo,
        float* __restrict__ out3, int m, int count) {
    const int b = blockIdx.x;
    const int w = threadIdx.x >> 6;
    const int lane = threadIdx.x & 63;
    const int lr = lane & 15;
    const int quad = lane >> 4;

    if (b < count) {
        h_unit(b, w, m, lr, quad, Thi, Tlo, Hhi, Hlo, out3);
    } else {
        r_unit(b - count, w, lr, quad, Rhi, Rlo, Thi, Tlo, Rnhi, Rnlo, Tnhi, Tnlo);
    }
}

// ---------------------------------------------------------------------------
// Observation GEMM v8: single dispatch (so its counters surface in the
// profiler top-5 above the ~185 us harness fills — the dur decomposition
// across v5/v6/v7 solves to obs ~300 us, 4-5x its ~65 us memory roofline,
// and we have never seen its counters). Body = v5 logic, BPITCH 272.
// ---------------------------------------------------------------------------
constexpr int BPITCH = 272;  // bytes per LDS row (256 data + 16 pad)

__global__ __launch_bounds__(512, 4) void obs_mfma_kernel(
        const __bf16* __restrict__ Hb,    // [T,C,S] (hi plane)
        const __bf16* __restrict__ pET,   // [N,S]
        const float* __restrict__ pcw,    // [T,C]
        float* __restrict__ out1,
        float* __restrict__ out2) {
    __shared__ __align__(16) unsigned char Bs[128 * BPITCH];  // 34 KB
    __shared__ float sw[8][C];

    const int tid = threadIdx.x;
    const int w = tid >> 6;
    const int lane = tid & 63;
    const int l31 = lane & 31;
    const int half = lane >> 5;
    const int nblk = blockIdx.x * 128;
    const int tbase = blockIdx.y * 8;
    const int t = tbase + w;           // wave owns one t, full 128-n width

    // Stage pET rows [nblk, nblk+128) into LDS (coalesced 16B chunks).
#pragma unroll
    for (int p = 0; p < 4; p++) {
        const int idx = p * 512 + tid;     // 0..2047
        const int row = idx >> 4;          // 0..127
        const int c16 = idx & 15;          // 16B chunk within row
        const float4 v = *reinterpret_cast<const float4*>(
            pET + (size_t)(nblk + row) * S + c16 * 8);
        *reinterpret_cast<float4*>(Bs + row * BPITCH + c16 * 16) = v;
    }
    if (tid < 256) sw[tid >> 5][tid & 31] =
        pcw[(size_t)(tbase + (tid >> 5)) * C + (tid & 31)];
    __syncthreads();

    const __bf16* A = Hb + (size_t)t * C * S;

    floatx16 acc[4];   // [ntile], 128 n-cols for one t
#pragma unroll
    for (int nt = 0; nt < 4; nt++) acc[nt] = (floatx16)0.f;

#pragma unroll
    for (int ks = 0; ks < 8; ks++) {
        const int ko = ks * 16 + half * 8;
        const bf16x8 a  = *reinterpret_cast<const bf16x8*>(&A[(size_t)l31 * S + ko]);
        const bf16x8 b0 = *reinterpret_cast<const bf16x8*>(Bs + (l31) * BPITCH + ko * 2);
        const bf16x8 b1 = *reinterpret_cast<const bf16x8*>(Bs + (32 + l31) * BPITCH + ko * 2);
        const bf16x8 b2 = *reinterpret_cast<const bf16x8*>(Bs + (64 + l31) * BPITCH + ko * 2);
        const bf16x8 b3 = *reinterpret_cast<const bf16x8*>(Bs + (96 + l31) * BPITCH + ko * 2);
        acc[0] = __builtin_amdgcn_mfma_f32_32x32x16_bf16(a, b0, acc[0], 0, 0, 0);
        acc[1] = __builtin_amdgcn_mfma_f32_32x32x16_bf16(a, b1, acc[1], 0, 0, 0);
        acc[2] = __builtin_amdgcn_mfma_f32_32x32x16_bf16(a, b2, acc[2], 0, 0, 0);
        acc[3] = __builtin_amdgcn_mfma_f32_32x32x16_bf16(a, b3, acc[3], 0, 0, 0);
    }

    float p0 = 0.f, p1 = 0.f, p2 = 0.f, p3 = 0.f;
#pragma unroll
    for (int reg = 0; reg < 16; reg++) {
        const int c = (reg & 3) + 8 * (reg >> 2) + 4 * half;
        const float wv = sw[w][c];
        const float o0 = acc[0][reg];
        const float o1 = acc[1][reg];
        const float o2 = acc[2][reg];
        const float o3 = acc[3][reg];
        float* rowp = &out2[((size_t)t * C + c) * N + nblk + l31];
        rowp[0]  = __logf(o0);
        rowp[32] = __logf(o1);
        rowp[64] = __logf(o2);
        rowp[96] = __logf(o3);
        p0 = fmaf(wv, o0, p0);
        p1 = fmaf(wv, o1, p1);
        p2 = fmaf(wv, o2, p2);
        p3 = fmaf(wv, o3, p3);
    }
    p0 += __shfl_xor(p0, 32, 64);
    p1 += __shfl_xor(p1, 32, 64);
    p2 += __shfl_xor(p2, 32, 64);
    p3 += __shfl_xor(p3, 32, 64);
    if (half == 0) {
        float* o1p = &out1[(size_t)t * N + nblk + l31];
        o1p[0]  = __logf(p0);
        o1p[32] = __logf(p1);
        o1p[64] = __logf(p2);
        o1p[96] = __logf(p3);
    }
}

// ---------------------------------------------------------------------------
extern "C" void kernel_launch(void* const* d_in, const int* in_sizes, int n_in,
                              void* d_out, int out_size, void* d_ws, size_t ws_size,
                              hipStream_t stream) {
    const float* in_init  = (const float*)d_in[0];  // [C,S]
    const float* in_cw    = (const float*)d_in[1];  // [T,C]
    const float* in_emis  = (const float*)d_in[2];  // [S,N]
    const float* in_trans = (const float*)d_in[3];  // [S,S]

    float* out = (float*)d_out;

    // Workspace layout (~9.5 MB, 256B aligned)
    char* wsb = (char*)d_ws;
    float*  ws_pcw = (float*)(wsb);                                  // 64 KB [T,C]
    __bf16* ws_pET = (__bf16*)(wsb + (64u << 10));                   // 1 MB  [N,S]
    __bf16* ws_Hhi = (__bf16*)(wsb + (1088u << 10));                 // 4 MB  [T,C,S]
    __bf16* ws_Hlo = (__bf16*)(wsb + (5184u << 10));                 // 4 MB  [T,C,S]
    __bf16* Pslot[2][4];
    for (int sl = 0; sl < 2; sl++)
        for (int pl = 0; pl < 4; pl++)
            Pslot[sl][pl] = (__bf16*)(wsb + (9280u << 10) + (size_t)(sl * 4 + pl) * (32u << 10));

    // 1) All softmaxes in one launch.
    fused_softmax_kernel<<<352, 256, 0, stream>>>(
        in_emis, in_cw, in_trans, in_init,
        out + OFF3, out + OFF4, out + OFF5,
        ws_pET, ws_pcw,
        Pslot[0][0], Pslot[0][1], Pslot[0][2], Pslot[0][3],
        ws_Hhi, ws_Hlo);

    // 2) H-doubling rounds: 9 per-round launches (measured optimum; the
    //    flag-sync and single-block fusions were 2.3x / 7.5x slower).
    for (int r = 1; r <= 9; r++) {
        const int m = 1 << (r - 1);
        const int count = (m < T - m) ? m : (T - m);
        const int extra = (r < 9) ? 8 : 0;
        const int s = (r - 1) & 1, d = r & 1;
        h_round_kernel<<<count + extra, 256, 0, stream>>>(
            Pslot[s][0], Pslot[s][1], Pslot[s][2], Pslot[s][3],
            Pslot[d][0], Pslot[d][1], Pslot[d][2], Pslot[d][3],
            ws_Hhi, ws_Hlo, out + OFF3, m, count);
    }

    // 3) Observation GEMM: single dispatch for counter visibility.
    obs_mfma_kernel<<<dim3(N / 128, T / 8), 512, 0, stream>>>(
        ws_Hhi, ws_pET, ws_pcw, out + OFF1, out + OFF2);
}

// Round 7
// 364.292 us; speedup vs baseline: 2.2978x; 1.0250x over previous
//
#include <hip/hip_runtime.h>
#include <hip/hip_bf16.h>
#include <cmath>

// Problem constants (fixed by setup_inputs)
constexpr int S = 128;   // num_states
constexpr int C = 32;    // num_chains
constexpr int N = 4096;  // num_nodes
constexpr int T = 512;   // num_iters

// Output layout (flat float32, concatenated in reference return order)
constexpr size_t OFF1 = 0;                          // log_observed_state_probs  [T,N]
constexpr size_t OFF2 = OFF1 + (size_t)T * N;       // log_observed_state_probs_ [T,C,N]
constexpr size_t OFF3 = OFF2 + (size_t)T * C * N;   // log_hidden_state_probs   [T,C,S]
constexpr size_t OFF4 = OFF3 + (size_t)T * C * S;   // log_emission             [S,N]
constexpr size_t OFF5 = OFF4 + (size_t)S * N;       // log_chain_weights        [T,C]

typedef __bf16 bf16x8 __attribute__((ext_vector_type(8)));
typedef float floatx4 __attribute__((ext_vector_type(4)));
typedef float floatx16 __attribute__((ext_vector_type(16)));

__device__ __forceinline__ void split_bf16(float p, __bf16& hi, __bf16& lo) {
    hi = (__bf16)p;
    lo = (__bf16)(p - (float)hi);
}

// ---------------------------------------------------------------------------
// Fused softmax kernel, one launch, 352 blocks x 256 threads (v5 form).
// ---------------------------------------------------------------------------
__global__ __launch_bounds__(256) void fused_softmax_kernel(
        const float* __restrict__ emis, const float* __restrict__ cw,
        const float* __restrict__ trans, const float* __restrict__ init,
        float* __restrict__ out3, float* __restrict__ out4, float* __restrict__ out5,
        __bf16* __restrict__ pET, float* __restrict__ pcw,
        __bf16* __restrict__ Rhi, __bf16* __restrict__ Rlo,
        __bf16* __restrict__ Thi, __bf16* __restrict__ Tlo,
        __bf16* __restrict__ Hhi, __bf16* __restrict__ Hlo) {
    const int b = blockIdx.x;
    const int tid = threadIdx.x;

    if (b >= 288) {   // ---- chain weights: 8 rows of 32 per block ----
        const int row = (b - 288) * 8 + (tid >> 5);
        const int j = tid & 31;
        const float v = cw[(size_t)row * C + j];
        float m = v;
#pragma unroll
        for (int o = 16; o > 0; o >>= 1) m = fmaxf(m, __shfl_xor(m, o, 64));
        float s = __expf(v - m);
#pragma unroll
        for (int o = 16; o > 0; o >>= 1) s += __shfl_xor(s, o, 64);
        const float lv = v - m - __logf(s);
        out5[(size_t)row * C + j] = lv;
        pcw[(size_t)row * C + j] = __expf(lv);
        return;
    }

    const float* x;
    int cols, row;
    if (b < 128)      { row = b;       cols = N; x = emis  + (size_t)row * N; }
    else if (b < 256) { row = b - 128; cols = S; x = trans + (size_t)row * S; }
    else              { row = b - 256; cols = S; x = init  + (size_t)row * S; }

    __shared__ float sm[4];
    __shared__ float ss[4];

    float m = -INFINITY;
    for (int j = tid; j < cols; j += 256) m = fmaxf(m, x[j]);
#pragma unroll
    for (int o = 32; o > 0; o >>= 1) m = fmaxf(m, __shfl_xor(m, o, 64));
    const int wid = tid >> 6;
    if ((tid & 63) == 0) sm[wid] = m;
    __syncthreads();
    m = fmaxf(fmaxf(sm[0], sm[1]), fmaxf(sm[2], sm[3]));

    float s = 0.f;
    for (int j = tid; j < cols; j += 256) s += __expf(x[j] - m);
#pragma unroll
    for (int o = 32; o > 0; o >>= 1) s += __shfl_xor(s, o, 64);
    if ((tid & 63) == 0) ss[wid] = s;
    __syncthreads();
    s = ss[0] + ss[1] + ss[2] + ss[3];
    const float lse = m + __logf(s);

    for (int j = tid; j < cols; j += 256) {
        const float v = x[j] - lse;
        const float p = __expf(v);
        if (b < 128) {
            out4[(size_t)row * N + j] = v;
            pET[(size_t)j * S + row] = (__bf16)p;
        } else if (b < 256) {
            __bf16 hi, lo; split_bf16(p, hi, lo);
            Rhi[(size_t)row * S + j] = hi; Rlo[(size_t)row * S + j] = lo;
            Thi[(size_t)j * S + row] = hi; Tlo[(size_t)j * S + row] = lo;
        } else {
            out3[((size_t)0 * C + row) * S + j] = v;
            __bf16 hi, lo; split_bf16(p, hi, lo);
            Hhi[(size_t)row * S + j] = hi; Hlo[(size_t)row * S + j] = lo;
        }
    }
}

// ---------------------------------------------------------------------------
// H-body for one (t, col-wave) unit — identical arithmetic to v5.
// ---------------------------------------------------------------------------
__device__ __forceinline__ void h_unit(
        int b, int w, int m, int lr, int quad,
        const __bf16* ThiS, const __bf16* TloS,
        __bf16* Hhi, __bf16* Hlo, float* out3) {
    const __bf16* Ahi = Hhi + (size_t)b * C * S;
    const __bf16* Alo = Hlo + (size_t)b * C * S;
    floatx4 acc[2][2];
#pragma unroll
    for (int mt = 0; mt < 2; mt++)
#pragma unroll
        for (int nt = 0; nt < 2; nt++) acc[mt][nt] = (floatx4)0.f;

#pragma unroll
    for (int kt = 0; kt < 4; kt++) {
        const int ko = kt * 32 + quad * 8;
        const bf16x8 ah0 = *reinterpret_cast<const bf16x8*>(&Ahi[(size_t)lr * S + ko]);
        const bf16x8 ah1 = *reinterpret_cast<const bf16x8*>(&Ahi[(size_t)(16 + lr) * S + ko]);
        const bf16x8 al0 = *reinterpret_cast<const bf16x8*>(&Alo[(size_t)lr * S + ko]);
        const bf16x8 al1 = *reinterpret_cast<const bf16x8*>(&Alo[(size_t)(16 + lr) * S + ko]);
        const bf16x8 bh0 = *reinterpret_cast<const bf16x8*>(&ThiS[(size_t)(w * 32 + lr) * S + ko]);
        const bf16x8 bh1 = *reinterpret_cast<const bf16x8*>(&ThiS[(size_t)(w * 32 + 16 + lr) * S + ko]);
        const bf16x8 bl0 = *reinterpret_cast<const bf16x8*>(&TloS[(size_t)(w * 32 + lr) * S + ko]);
        const bf16x8 bl1 = *reinterpret_cast<const bf16x8*>(&TloS[(size_t)(w * 32 + 16 + lr) * S + ko]);
        acc[0][0] = __builtin_amdgcn_mfma_f32_16x16x32_bf16(ah0, bh0, acc[0][0], 0, 0, 0);
        acc[0][0] = __builtin_amdgcn_mfma_f32_16x16x32_bf16(ah0, bl0, acc[0][0], 0, 0, 0);
        acc[0][0] = __builtin_amdgcn_mfma_f32_16x16x32_bf16(al0, bh0, acc[0][0], 0, 0, 0);
        acc[0][1] = __builtin_amdgcn_mfma_f32_16x16x32_bf16(ah0, bh1, acc[0][1], 0, 0, 0);
        acc[0][1] = __builtin_amdgcn_mfma_f32_16x16x32_bf16(ah0, bl1, acc[0][1], 0, 0, 0);
        acc[0][1] = __builtin_amdgcn_mfma_f32_16x16x32_bf16(al0, bh1, acc[0][1], 0, 0, 0);
        acc[1][0] = __builtin_amdgcn_mfma_f32_16x16x32_bf16(ah1, bh0, acc[1][0], 0, 0, 0);
        acc[1][0] = __builtin_amdgcn_mfma_f32_16x16x32_bf16(ah1, bl0, acc[1][0], 0, 0, 0);
        acc[1][0] = __builtin_amdgcn_mfma_f32_16x16x32_bf16(al1, bh0, acc[1][0], 0, 0, 0);
        acc[1][1] = __builtin_amdgcn_mfma_f32_16x16x32_bf16(ah1, bh1, acc[1][1], 0, 0, 0);
        acc[1][1] = __builtin_amdgcn_mfma_f32_16x16x32_bf16(ah1, bl1, acc[1][1], 0, 0, 0);
        acc[1][1] = __builtin_amdgcn_mfma_f32_16x16x32_bf16(al1, bh1, acc[1][1], 0, 0, 0);
    }

    const size_t t = (size_t)m + b;
#pragma unroll
    for (int mt = 0; mt < 2; mt++) {
#pragma unroll
        for (int nt = 0; nt < 2; nt++) {
#pragma unroll
            for (int reg = 0; reg < 4; reg++) {
                const int c = mt * 16 + quad * 4 + reg;
                const int n = w * 32 + nt * 16 + lr;
                const float p = acc[mt][nt][reg];
                __bf16 hi, lo; split_bf16(p, hi, lo);
                Hhi[(t * C + c) * S + n] = hi;
                Hlo[(t * C + c) * S + n] = lo;
                out3[(t * C + c) * S + n] = __logf(p);
            }
        }
    }
}

// R-squaring body for one (row-block, col-wave) unit — identical to v5.
__device__ __forceinline__ void r_unit(
        int rb, int w, int lr, int quad,
        const __bf16* RhiS, const __bf16* RloS,
        const __bf16* ThiS, const __bf16* TloS,
        __bf16* RhiD, __bf16* RloD, __bf16* ThiD, __bf16* TloD) {
    floatx4 acc[2];
    acc[0] = (floatx4)0.f; acc[1] = (floatx4)0.f;
#pragma unroll
    for (int kt = 0; kt < 4; kt++) {
        const int ko = kt * 32 + quad * 8;
        const bf16x8 ah = *reinterpret_cast<const bf16x8*>(&RhiS[(size_t)(rb * 16 + lr) * S + ko]);
        const bf16x8 al = *reinterpret_cast<const bf16x8*>(&RloS[(size_t)(rb * 16 + lr) * S + ko]);
        const bf16x8 bh0 = *reinterpret_cast<const bf16x8*>(&ThiS[(size_t)(w * 32 + lr) * S + ko]);
        const bf16x8 bh1 = *reinterpret_cast<const bf16x8*>(&ThiS[(size_t)(w * 32 + 16 + lr) * S + ko]);
        const bf16x8 bl0 = *reinterpret_cast<const bf16x8*>(&TloS[(size_t)(w * 32 + lr) * S + ko]);
        const bf16x8 bl1 = *reinterpret_cast<const bf16x8*>(&TloS[(size_t)(w * 32 + 16 + lr) * S + ko]);
        acc[0] = __builtin_amdgcn_mfma_f32_16x16x32_bf16(ah, bh0, acc[0], 0, 0, 0);
        acc[0] = __builtin_amdgcn_mfma_f32_16x16x32_bf16(ah, bl0, acc[0], 0, 0, 0);
        acc[0] = __builtin_amdgcn_mfma_f32_16x16x32_bf16(al, bh0, acc[0], 0, 0, 0);
        acc[1] = __builtin_amdgcn_mfma_f32_16x16x32_bf16(ah, bh1, acc[1], 0, 0, 0);
        acc[1] = __builtin_amdgcn_mfma_f32_16x16x32_bf16(ah, bl1, acc[1], 0, 0, 0);
        acc[1] = __builtin_amdgcn_mfma_f32_16x16x32_bf16(al, bh1, acc[1], 0, 0, 0);
    }
#pragma unroll
    for (int nt = 0; nt < 2; nt++) {
#pragma unroll
        for (int reg = 0; reg < 4; reg++) {
            const int row = rb * 16 + quad * 4 + reg;
            const int col = w * 32 + nt * 16 + lr;
            const float p = acc[nt][reg];
            __bf16 hi, lo; split_bf16(p, hi, lo);
            RhiD[(size_t)row * S + col] = hi; RloD[(size_t)row * S + col] = lo;
            ThiD[(size_t)col * S + row] = hi; TloD[(size_t)col * S + row] = lo;
        }
    }
}

// ---------------------------------------------------------------------------
// One H-doubling round (v5-proven launch structure; the flag-sync variant
// was 2.3x slower and the single-block fusion 7.5x slower — per-round
// launches are the measured optimum for this serial ladder).
// ---------------------------------------------------------------------------
__global__ __launch_bounds__(256) void h_round_kernel(
        const __bf16* __restrict__ Rhi, const __bf16* __restrict__ Rlo,
        const __bf16* __restrict__ Thi, const __bf16* __restrict__ Tlo,
        __bf16* __restrict__ Rnhi, __bf16* __restrict__ Rnlo,
        __bf16* __restrict__ Tnhi, __bf16* __restrict__ Tnlo,
        __bf16* __restrict__ Hhi, __bf16* __restrict__ Hlo,
        float* __restrict__ out3, int m, int count) {
    const int b = blockIdx.x;
    const int w = threadIdx.x >> 6;
    const int lane = threadIdx.x & 63;
    const int lr = lane & 15;
    const int quad = lane >> 4;

    if (b < count) {
        h_unit(b, w, m, lr, quad, Thi, Tlo, Hhi, Hlo, out3);
    } else {
        r_unit(b - count, w, lr, quad, Rhi, Rlo, Thi, Tlo, Rnhi, Rnlo, Tnhi, Tnlo);
    }
}

// ---------------------------------------------------------------------------
// Observation GEMM v9: block owns (128 n x 32 t) — stages the pET tile ONCE
// and loops 4 t-group iterations over it. Deltas vs v8:
//   - pET LDS-staging traffic 64 MB -> 16 MB; stage barriers 2048 -> 512
//   - blocks 2048 -> 512 (= exactly 2/CU), smaller dispatch tail
//   - successive iterations' A-loads overlap prior epilogues (VMEM queue)
//   - BPITCH back to 264 (2-lane start-bank sharing = free per bank model;
//     272's 4-way grouping measured slightly worse in v8)
// Theory: obs (~125 us vs ~55 us traffic roofline) is staging/latency-bound,
// not store-bound (v4/v5 store experiments: -6 us each).
// ---------------------------------------------------------------------------
constexpr int BPITCH = 264;  // bytes per LDS row (256 data + 8 pad)

__global__ __launch_bounds__(512, 4) void obs_mfma_kernel(
        const __bf16* __restrict__ Hb,    // [T,C,S] (hi plane)
        const __bf16* __restrict__ pET,   // [N,S]
        const float* __restrict__ pcw,    // [T,C]
        float* __restrict__ out1,
        float* __restrict__ out2) {
    __shared__ __align__(16) unsigned char Bs[128 * BPITCH];  // 33 KB
    __shared__ float sw[32][C];                               // 4 KB

    const int tid = threadIdx.x;
    const int w = tid >> 6;
    const int lane = tid & 63;
    const int l31 = lane & 31;
    const int half = lane >> 5;
    const int nblk = blockIdx.x * 128;
    const int tg = blockIdx.y * 32;    // block covers t in [tg, tg+32)

    // Stage pET rows [nblk, nblk+128) into LDS once (coalesced 16B chunks).
#pragma unroll
    for (int p = 0; p < 4; p++) {
        const int idx = p * 512 + tid;     // 0..2047
        const int row = idx >> 4;          // 0..127
        const int c16 = idx & 15;          // 16B chunk within row
        const float4 v = *reinterpret_cast<const float4*>(
            pET + (size_t)(nblk + row) * S + c16 * 8);
        *reinterpret_cast<float4*>(Bs + row * BPITCH + c16 * 16) = v;
    }
    // Stage pcw for all 32 t's (1024 floats, 2 per thread).
#pragma unroll
    for (int i = tid; i < 32 * C; i += 512)
        (&sw[0][0])[i] = pcw[(size_t)(tg + (i >> 5)) * C + (i & 31)];
    __syncthreads();

#pragma unroll 1
    for (int it = 0; it < 4; ++it) {
        const int t = tg + it * 8 + w;     // wave owns one t per iteration
        const __bf16* A = Hb + (size_t)t * C * S;

        floatx16 acc[4];
#pragma unroll
        for (int nt = 0; nt < 4; nt++) acc[nt] = (floatx16)0.f;

#pragma unroll
        for (int ks = 0; ks < 8; ks++) {
            const int ko = ks * 16 + half * 8;
            const bf16x8 a  = *reinterpret_cast<const bf16x8*>(&A[(size_t)l31 * S + ko]);
            const bf16x8 b0 = *reinterpret_cast<const bf16x8*>(Bs + (l31) * BPITCH + ko * 2);
            const bf16x8 b1 = *reinterpret_cast<const bf16x8*>(Bs + (32 + l31) * BPITCH + ko * 2);
            const bf16x8 b2 = *reinterpret_cast<const bf16x8*>(Bs + (64 + l31) * BPITCH + ko * 2);
            const bf16x8 b3 = *reinterpret_cast<const bf16x8*>(Bs + (96 + l31) * BPITCH + ko * 2);
            acc[0] = __builtin_amdgcn_mfma_f32_32x32x16_bf16(a, b0, acc[0], 0, 0, 0);
            acc[1] = __builtin_amdgcn_mfma_f32_32x32x16_bf16(a, b1, acc[1], 0, 0, 0);
            acc[2] = __builtin_amdgcn_mfma_f32_32x32x16_bf16(a, b2, acc[2], 0, 0, 0);
            acc[3] = __builtin_amdgcn_mfma_f32_32x32x16_bf16(a, b3, acc[3], 0, 0, 0);
        }

        float p0 = 0.f, p1 = 0.f, p2 = 0.f, p3 = 0.f;
#pragma unroll
        for (int reg = 0; reg < 16; reg++) {
            const int c = (reg & 3) + 8 * (reg >> 2) + 4 * half;
            const float wv = sw[it * 8 + w][c];
            const float o0 = acc[0][reg];
            const float o1 = acc[1][reg];
            const float o2 = acc[2][reg];
            const float o3 = acc[3][reg];
            float* rowp = &out2[((size_t)t * C + c) * N + nblk + l31];
            rowp[0]  = __logf(o0);
            rowp[32] = __logf(o1);
            rowp[64] = __logf(o2);
            rowp[96] = __logf(o3);
            p0 = fmaf(wv, o0, p0);
            p1 = fmaf(wv, o1, p1);
            p2 = fmaf(wv, o2, p2);
            p3 = fmaf(wv, o3, p3);
        }
        p0 += __shfl_xor(p0, 32, 64);
        p1 += __shfl_xor(p1, 32, 64);
        p2 += __shfl_xor(p2, 32, 64);
        p3 += __shfl_xor(p3, 32, 64);
        if (half == 0) {
            float* o1p = &out1[(size_t)t * N + nblk + l31];
            o1p[0]  = __logf(p0);
            o1p[32] = __logf(p1);
            o1p[64] = __logf(p2);
            o1p[96] = __logf(p3);
        }
        // No __syncthreads needed between iterations: Bs and sw are
        // read-only after the initial barrier.
    }
}

// ---------------------------------------------------------------------------
extern "C" void kernel_launch(void* const* d_in, const int* in_sizes, int n_in,
                              void* d_out, int out_size, void* d_ws, size_t ws_size,
                              hipStream_t stream) {
    const float* in_init  = (const float*)d_in[0];  // [C,S]
    const float* in_cw    = (const float*)d_in[1];  // [T,C]
    const float* in_emis  = (const float*)d_in[2];  // [S,N]
    const float* in_trans = (const float*)d_in[3];  // [S,S]

    float* out = (float*)d_out;

    // Workspace layout (~9.5 MB, 256B aligned)
    char* wsb = (char*)d_ws;
    float*  ws_pcw = (float*)(wsb);                                  // 64 KB [T,C]
    __bf16* ws_pET = (__bf16*)(wsb + (64u << 10));                   // 1 MB  [N,S]
    __bf16* ws_Hhi = (__bf16*)(wsb + (1088u << 10));                 // 4 MB  [T,C,S]
    __bf16* ws_Hlo = (__bf16*)(wsb + (5184u << 10));                 // 4 MB  [T,C,S]
    __bf16* Pslot[2][4];
    for (int sl = 0; sl < 2; sl++)
        for (int pl = 0; pl < 4; pl++)
            Pslot[sl][pl] = (__bf16*)(wsb + (9280u << 10) + (size_t)(sl * 4 + pl) * (32u << 10));

    // 1) All softmaxes in one launch.
    fused_softmax_kernel<<<352, 256, 0, stream>>>(
        in_emis, in_cw, in_trans, in_init,
        out + OFF3, out + OFF4, out + OFF5,
        ws_pET, ws_pcw,
        Pslot[0][0], Pslot[0][1], Pslot[0][2], Pslot[0][3],
        ws_Hhi, ws_Hlo);

    // 2) H-doubling rounds: 9 per-round launches (measured optimum).
    for (int r = 1; r <= 9; r++) {
        const int m = 1 << (r - 1);
        const int count = (m < T - m) ? m : (T - m);
        const int extra = (r < 9) ? 8 : 0;
        const int s = (r - 1) & 1, d = r & 1;
        h_round_kernel<<<count + extra, 256, 0, stream>>>(
            Pslot[s][0], Pslot[s][1], Pslot[s][2], Pslot[s][3],
            Pslot[d][0], Pslot[d][1], Pslot[d][2], Pslot[d][3],
            ws_Hhi, ws_Hlo, out + OFF3, m, count);
    }

    // 3) Observation GEMM v9: 4 t-groups per block, pET staged once.
    obs_mfma_kernel<<<dim3(N / 128, T / 32), 512, 0, stream>>>(
        ws_Hhi, ws_pET, ws_pcw, out + OFF1, out + OFF2);
}